// Round 2
// baseline (671.214 us; speedup 1.0000x reference)
//
#include <hip/hip_runtime.h>
#include <hip/hip_bf16.h>
#include <math.h>

#define B_ 256
#define L_ 64
#define R_ 1024
#define A_ 512
#define E_ 1024
#define BR (B_ * R_)

typedef __attribute__((ext_vector_type(8))) short short8;
typedef __attribute__((ext_vector_type(4))) float f32x4;

__device__ __forceinline__ unsigned int pkbf(float x, float y) {
    union { __hip_bfloat162 h; unsigned int u; } cv;
    cv.h = __float22bfloat162_rn(make_float2(x, y));
    return cv.u;
}

__device__ __forceinline__ float tanh_fast(float x) {
    return 1.f - 2.f / (1.f + __expf(2.f * x));
}
__device__ __forceinline__ float sigm_(float x) { return 1.f / (1.f + __expf(-x)); }

// async global->LDS, 16B per lane, dest = wave-uniform base + lane*16
__device__ __forceinline__ void gl16(const float* g, float* l) {
    __builtin_amdgcn_global_load_lds(
        (const __attribute__((address_space(1))) void*)g,
        (__attribute__((address_space(3))) void*)l, 16, 0, 0);
}

__device__ __forceinline__ short8 pack8(f32x4 a, f32x4 b) {
    union { unsigned int u[4]; short8 s; } r;
    r.u[0] = pkbf(a[0], a[1]); r.u[1] = pkbf(a[2], a[3]);
    r.u[2] = pkbf(b[0], b[1]); r.u[3] = pkbf(b[2], b[3]);
    return r.s;
}

// XCD-aware bijective block swizzle (all grids are %8==0): each XCD gets a
// contiguous chunk of the original linear block order -> bn-siblings sharing
// an A-panel co-reside on one XCD L2.  (R1: cut FETCH 133->41 MB, keep.)
__device__ __forceinline__ void swz3(int& bx, int& by, int& bz) {
    int gx = gridDim.x, gy = gridDim.y, gz = gridDim.z;
    int id = (blockIdx.z * gy + blockIdx.y) * gx + blockIdx.x;
    int nwg = gx * gy * gz;
    id = (id & 7) * (nwg >> 3) + (id >> 3);
    bx = id % gx; id /= gx;
    by = id % gy; bz = id / gy;
}

// ---------------------------------------------------------------------------
// bf16 MFMA GEMM core, 128x128 tile, BK=32. fp32 tiles staged DIRECTLY to LDS
// via global_load_lds (16B), double-buffered.
// R2: T4 counted vmcnt — raw s_barrier + "s_waitcnt vmcnt(8)" so the 8
// just-issued prefetch loads for tile k+1 stay in flight ACROSS the barrier
// (never drain to 0 in the main loop). __syncthreads drained vmcnt(0) and
// killed the pipeline in R1.
// Race safety (2 buffers, 2 barriers/iter): buf[k&1] is overwritten only by
// the STAGE at top of iter k+1, which every wave reaches only after the
// end-of-iter-k barrier, which follows consumption of all ds_reads of
// buf[k&1] (register dep -> lgkmcnt before MFMA). sched_barrier(0) pins the
// ds_reads inside the barrier pair (rule #18).
// ---------------------------------------------------------------------------
__device__ __forceinline__ void mm_core(const float* __restrict__ Abm, int lda,
                                        const float* __restrict__ Wbn, int ldw,
                                        int K, f32x4 acc[4][4])
{
    __shared__ float As[2][4096];   // [buf][128 rows x 32 cols fp32]
    __shared__ float Ws[2][4096];

    const int t = threadIdx.x;
    const int w = t >> 6, lane = t & 63;

    // ---- staging map: wave w, call r covers rows 32r+8w .. +7 (1KB/wave/call)
    const int lr = lane >> 3;           // == (dest row) & 7
    const int csw = (lane & 7) ^ lr;    // swizzled source col-chunk (16B units)
    const float* pa[4];
    const float* pw[4];
    int ldst[4];
#pragma unroll
    for (int r = 0; r < 4; ++r) {
        int row = 32 * r + 8 * w + lr;
        pa[r] = Abm + (size_t)row * lda + csw * 4;
        pw[r] = Wbn + (size_t)row * ldw + csw * 4;
        ldst[r] = w * 256 + r * 1024;   // float index, wave-uniform
    }
#define MMC_STAGE(buf, kof) do { _Pragma("unroll") \
    for (int r = 0; r < 4; ++r) { \
        gl16(pa[r] + (kof), &As[buf][ldst[r]]); \
        gl16(pw[r] + (kof), &Ws[buf][ldst[r]]); } } while (0)

    // ---- consumer fragment addresses (chunk c read at physical c^(row&7))
    const int m0 = (w >> 1) * 64, n0 = (w & 1) * 64;
    const int lrow = lane & 15, quad = lane >> 4;
    int ai[4], wi[4];
#pragma unroll
    for (int i = 0; i < 4; ++i) {
        int ra = m0 + i * 16 + lrow;
        ai[i] = ra * 32 + ((((quad << 1) ^ (lrow & 7)) & 7) << 2);
        int rw = n0 + i * 16 + lrow;
        wi[i] = rw * 32 + ((((quad << 1) ^ (lrow & 7)) & 7) << 2);
    }

    const int n = K >> 5;
    MMC_STAGE(0, 0);
    for (int k = 0; k < n; ++k) {
        if (k + 1 < n) {
            MMC_STAGE((k + 1) & 1, (k + 1) * 32);      // fire-and-forget, 8 ops
            asm volatile("s_waitcnt vmcnt(8)" ::: "memory");  // tile k landed,
                                                              // tile k+1 in flight
        } else {
            asm volatile("s_waitcnt vmcnt(0)" ::: "memory");  // drain at tail
        }
        __builtin_amdgcn_s_barrier();                  // buf[k&1] visible to all
        __builtin_amdgcn_sched_barrier(0);
        const float* Ab = As[k & 1];
        const float* Wb = Ws[k & 1];
        short8 af[4], wf[4];
#pragma unroll
        for (int i = 0; i < 4; ++i) {
            f32x4 a0 = *(const f32x4*)(Ab + ai[i]);
            f32x4 a1 = *(const f32x4*)(Ab + (ai[i] ^ 4));   // chunk c^1
            af[i] = pack8(a0, a1);
            f32x4 w0 = *(const f32x4*)(Wb + wi[i]);
            f32x4 w1 = *(const f32x4*)(Wb + (wi[i] ^ 4));
            wf[i] = pack8(w0, w1);
        }
#pragma unroll
        for (int mt = 0; mt < 4; ++mt)
#pragma unroll
            for (int nt = 0; nt < 4; ++nt)
                acc[mt][nt] = __builtin_amdgcn_mfma_f32_16x16x32_bf16(
                    af[mt], wf[nt], acc[mt][nt], 0, 0, 0);
        __builtin_amdgcn_sched_barrier(0);             // pin reads above B2
        __builtin_amdgcn_s_barrier();                  // all done reading buf[k&1]
    }
#undef MMC_STAGE
}

__device__ __forceinline__ void mm_store(f32x4 acc[4][4], float* __restrict__ Cbm,
                                         int ldc, int bn, const float* __restrict__ bias)
{
    const int t = threadIdx.x;
    const int w = t >> 6, lane = t & 63;
    const int m0 = (w >> 1) * 64, n0 = (w & 1) * 64;
    const int lrow = lane & 15, quad = lane >> 4;
#pragma unroll
    for (int nt = 0; nt < 4; ++nt) {
        int col = bn + n0 + nt * 16 + lrow;
        float bv = bias ? bias[col] : 0.f;
#pragma unroll
        for (int mt = 0; mt < 4; ++mt) {
            int rbase = m0 + mt * 16 + quad * 4;
#pragma unroll
            for (int r = 0; r < 4; ++r)
                Cbm[(size_t)(rbase + r) * ldc + col] = acc[mt][nt][r] + bv;
        }
    }
}

// Fused attention-logit epilogue: lpart[bn_tile][row] = sum_a tanh(...)*wa[a]
__device__ __forceinline__ void attn_epilogue(
    f32x4 acc[4][4], int bm, int bn, int M, int L,
    const float* __restrict__ base, const float* __restrict__ base2,
    const float* __restrict__ wbias, const float* __restrict__ wa,
    float sign, float* __restrict__ lpart)
{
    __shared__ float lsum[2][128];
    const int t = threadIdx.x;
    const int w = t >> 6, lane = t & 63;
    const int m0 = (w >> 1) * 64, n0 = (w & 1) * 64;
    const int lrow = lane & 15, quad = lane >> 4;
    float wav[4], wbv[4];
    int colv[4];
#pragma unroll
    for (int nt = 0; nt < 4; ++nt) {
        colv[nt] = bn + n0 + nt * 16 + lrow;
        wav[nt] = wa[colv[nt]];
        wbv[nt] = wbias ? wbias[colv[nt]] : 0.f;
    }
#pragma unroll
    for (int mt = 0; mt < 4; ++mt) {
#pragma unroll
        for (int r = 0; r < 4; ++r) {
            int rl = m0 + mt * 16 + quad * 4 + r;
            int row = bm + rl;
            int b = row / L;
            const float* bp = base + (size_t)b * A_;
            const float* bp2 = base2 ? base2 + (size_t)b * A_ : nullptr;
            float s = 0.f;
#pragma unroll
            for (int nt = 0; nt < 4; ++nt) {
                float v = bp[colv[nt]] + wbv[nt] + sign * acc[mt][nt][r];
                if (bp2) v += bp2[colv[nt]];
                s += tanh_fast(v) * wav[nt];
            }
            s += __shfl_xor(s, 1);
            s += __shfl_xor(s, 2);
            s += __shfl_xor(s, 4);
            s += __shfl_xor(s, 8);
            if (lrow == 0) lsum[w & 1][rl] = s;
        }
    }
    __syncthreads();
    if (t < 128)
        lpart[(size_t)(bn >> 7) * M + bm + t] = lsum[0][t] + lsum[1][t];
}

// ---------------------------------------------------------------------------
// GEMM kernels
// ---------------------------------------------------------------------------
struct Seg8 { const float* A[8]; const float* W[8]; int lda[8]; int ldw[8]; };

// K-segmented split-K GEMM (LSTM gates): partials to Cbase + z*zstride
__global__ __launch_bounds__(256) void mm_seg(Seg8 s, float* __restrict__ Cbase,
                                              int ldc, int kchunk, int zstride)
{
    int bx, by, bz;
    swz3(bx, by, bz);
    int z = bz;
    int bm = by * 128, bn = bx * 128;
    f32x4 acc[4][4];
#pragma unroll
    for (int i = 0; i < 4; ++i)
#pragma unroll
        for (int j = 0; j < 4; ++j) acc[i][j] = (f32x4)0.f;
    mm_core(s.A[z] + (size_t)bm * s.lda[z], s.lda[z],
            s.W[z] + (size_t)bn * s.ldw[z], s.ldw[z], kchunk, acc);
    mm_store(acc, Cbase + (size_t)z * zstride + (size_t)bm * ldc, ldc, bn, nullptr);
}

// batched small GEMMs (M=256, N=512, K=1024, lda=ldw=1024, ldc=512)
struct Jobs4 { const float* A[4]; const float* W[4]; const float* bias[4]; float* C[4]; };
__global__ __launch_bounds__(256) void mm_jobs(Jobs4 p, int K)
{
    int bx, by, bz;
    swz3(bx, by, bz);
    int z = bz;
    int bm = by * 128, bn = bx * 128;
    f32x4 acc[4][4];
#pragma unroll
    for (int i = 0; i < 4; ++i)
#pragma unroll
        for (int j = 0; j < 4; ++j) acc[i][j] = (f32x4)0.f;
    mm_core(p.A[z] + (size_t)bm * 1024, 1024, p.W[z] + (size_t)bn * 1024, 1024, K, acc);
    mm_store(acc, p.C[z] + (size_t)bm * 512, 512, bn, p.bias[z]);
}

// GEMM + fused tanh-logit reduction (no C write at all)
__global__ __launch_bounds__(256) void mm_fused_attn(
    const float* __restrict__ A, int lda, const float* __restrict__ W, int ldw, int K,
    const float* __restrict__ base, const float* __restrict__ base2,
    const float* __restrict__ wbias, const float* __restrict__ wa,
    float sign, int M, int L, float* __restrict__ lpart)
{
    int bx, by, bz;
    swz3(bx, by, bz);
    int bm = by * 128, bn = bx * 128;
    f32x4 acc[4][4];
#pragma unroll
    for (int i = 0; i < 4; ++i)
#pragma unroll
        for (int j = 0; j < 4; ++j) acc[i][j] = (f32x4)0.f;
    mm_core(A + (size_t)bm * lda, lda, W + (size_t)bn * ldw, ldw, K, acc);
    attn_epilogue(acc, bm, bn, M, L, base, base2, wbias, wa, sign, lpart);
}

// ---------------------------------------------------------------------------
// pointwise kernels
// ---------------------------------------------------------------------------
__global__ __launch_bounds__(256) void attn_logits_sp(
    const float* __restrict__ base, const float* __restrict__ proj,
    const float* __restrict__ wa, float* __restrict__ logits)
{
    int idx = blockIdx.x * 4 + (threadIdx.x >> 6);   // b*64+l
    int lane = threadIdx.x & 63;
    int b = idx >> 6;
    const f32x4* p = (const f32x4*)(proj + (size_t)idx * A_);
    const f32x4* bs = (const f32x4*)(base + (size_t)b * A_);
    const f32x4* wv = (const f32x4*)wa;
    float acc = 0.f;
#pragma unroll
    for (int i = 0; i < 2; ++i) {
        int a = i * 64 + lane;
        f32x4 pv = p[a], bv = bs[a], w4 = wv[a];
#pragma unroll
        for (int j = 0; j < 4; ++j) acc += tanh_fast(bv[j] + pv[j]) * w4[j];
    }
#pragma unroll
    for (int off = 32; off > 0; off >>= 1) acc += __shfl_xor(acc, off);
    if (lane == 0) logits[idx] = acc;
}

// softmax over L (<=64) per group, summing np logit partials
__global__ __launch_bounds__(256) void softmax_part(
    const float* __restrict__ lpart, int np, int M, int L, float* __restrict__ attw)
{
    int grp = blockIdx.x * 4 + (threadIdx.x >> 6);
    int lane = threadIdx.x & 63;
    int row = grp * L + lane;
    float v = -INFINITY;
    if (lane < L) {
        float s = 0.f;
        for (int p = 0; p < np; ++p) s += lpart[(size_t)p * M + row];
        v = s;
    }
    float m = v;
#pragma unroll
    for (int off = 32; off > 0; off >>= 1) m = fmaxf(m, __shfl_xor(m, off));
    float e = (lane < L) ? __expf(v - m) : 0.f;
    float s = e;
#pragma unroll
    for (int off = 32; off > 0; off >>= 1) s += __shfl_xor(s, off);
    if (lane < L) attw[row] = e / s;
}

// out[b,:] = sum_l w[b,l] * V[b,l,:]
__global__ void ws_one(const float* __restrict__ wgt, const float* __restrict__ V,
                       float* __restrict__ out)
{
    int idx = blockIdx.x * blockDim.x + threadIdx.x;   // B*256 (float4 lanes)
    int b = idx >> 8, d4 = idx & 255;
    const f32x4* vp = (const f32x4*)(V + (size_t)b * L_ * R_) + d4;
    const float* wp = wgt + b * L_;
    f32x4 acc = (f32x4)0.f;
    for (int l = 0; l < L_; ++l) acc += wp[l] * vp[(size_t)l * 256];
    ((f32x4*)out)[idx] = acc;
}

// single pass over roi: out1 = sum w1*V ; out2 = ctx - sum w2*V
__global__ void ws_dual(const float* __restrict__ w1, const float* __restrict__ w2,
                        const float* __restrict__ V, const float* __restrict__ ctx,
                        float* __restrict__ out1, float* __restrict__ out2)
{
    int idx = blockIdx.x * blockDim.x + threadIdx.x;
    int b = idx >> 8, d4 = idx & 255;
    const f32x4* vp = (const f32x4*)(V + (size_t)b * L_ * R_) + d4;
    const float* p1 = w1 + b * L_;
    const float* p2 = w2 + b * L_;
    f32x4 a1 = (f32x4)0.f, a2 = (f32x4)0.f;
    for (int l = 0; l < L_; ++l) {
        f32x4 v = vp[(size_t)l * 256];
        a1 += p1[l] * v;
        a2 += p2[l] * v;
    }
    ((f32x4*)out1)[idx] = a1;
    ((f32x4*)out2)[idx] = ((const f32x4*)ctx)[idx] - a2;
}

__global__ void ws_out_k(const float* __restrict__ wgt, const float* __restrict__ f3,
                         float* __restrict__ out)
{
    int idx = blockIdx.x * blockDim.x + threadIdx.x;   // B*256
    int b = idx >> 8, d4 = idx & 255;
    const f32x4* fp = (const f32x4*)f3;
    f32x4 acc = (f32x4)0.f;
#pragma unroll
    for (int j = 0; j < 3; ++j)
        acc += wgt[b * 3 + j] * fp[(size_t)(b * 3 + j) * 256 + d4];
    ((f32x4*)out)[idx] = acc;
}

__global__ void build_feats3(const float* __restrict__ sf, const float* __restrict__ cf,
                             const float* __restrict__ fc, float* __restrict__ f3)
{
    int idx = blockIdx.x * blockDim.x + threadIdx.x;   // B*3*256
    int d4 = idx & 255;
    int tt = idx >> 8;
    int j = tt % 3, b = tt / 3;
    const float* src = (j == 0) ? sf : (j == 1) ? cf : fc;
    ((f32x4*)f3)[idx] = ((const f32x4*)(src + (size_t)b * R_))[d4];
}

// LSTM pointwise summing P split-K partials + both biases (float4)
__global__ void lstm_pw(const float* __restrict__ gp, int P,
                        const float* __restrict__ b_ih, const float* __restrict__ b_hh,
                        const float* __restrict__ c_prev,
                        float* __restrict__ h_out, float* __restrict__ h_out2,
                        float* __restrict__ c_out)
{
    int idx = blockIdx.x * blockDim.x + threadIdx.x;   // B*256
    int b = idx >> 8, r4 = idx & 255;
    f32x4 g[4];
#pragma unroll
    for (int gi = 0; gi < 4; ++gi) {
        int o = gi * 256 + r4;
        f32x4 s = ((const f32x4*)b_ih)[o] + ((const f32x4*)b_hh)[o];
        for (int p = 0; p < P; ++p)
            s += ((const f32x4*)(gp + (size_t)p * B_ * 4096 + (size_t)b * 4096))[o];
        g[gi] = s;
    }
    f32x4 cp = ((const f32x4*)c_prev)[idx];
    f32x4 c2, h2;
#pragma unroll
    for (int j = 0; j < 4; ++j) {
        float cc = sigm_(g[1][j]) * cp[j] + sigm_(g[0][j]) * tanh_fast(g[2][j]);
        c2[j] = cc;
        h2[j] = sigm_(g[3][j]) * tanh_fast(cc);
    }
    ((f32x4*)c_out)[idx] = c2;
    ((f32x4*)h_out)[idx] = h2;
    if (h_out2) ((f32x4*)h_out2)[idx] = h2;
}

// ---------------------------------------------------------------------------
extern "C" void kernel_launch(void* const* d_in, const int* in_sizes, int n_in,
                              void* d_out, int out_size, void* d_ws, size_t ws_size,
                              hipStream_t stream)
{
    const float* xt      = (const float*)d_in[0];
    const float* fc      = (const float*)d_in[1];
    const float* roi     = (const float*)d_in[2];
    const float* p_roi   = (const float*)d_in[3];
    const float* ctxf    = (const float*)d_in[4];
    const float* sh      = (const float*)d_in[5];
    const float* sc      = (const float*)d_in[6];
    const float* W_ih_v  = (const float*)d_in[7];
    const float* W_hh_v  = (const float*)d_in[8];
    const float* b_ih_v  = (const float*)d_in[9];
    const float* b_hh_v  = (const float*)d_in[10];
    const float* W_ih_l  = (const float*)d_in[11];
    const float* W_hh_l  = (const float*)d_in[12];
    const float* b_ih_l  = (const float*)d_in[13];
    const float* b_hh_l  = (const float*)d_in[14];
    const float* sp_wh_w = (const float*)d_in[15];
    const float* sp_wh_b = (const float*)d_in[16];
    const float* sp_wa_w = (const float*)d_in[17];
    const float* ctx_wh_w= (const float*)d_in[19];
    const float* ctx_wh_b= (const float*)d_in[20];
    const float* ctx_wv_w= (const float*)d_in[21];
    const float* ctx_wv_b= (const float*)d_in[22];
    const float* ctx_wa_w= (const float*)d_in[23];
    const float* cmp_wh_w= (const float*)d_in[25];
    const float* cmp_wh_b= (const float*)d_in[26];
    const float* cmp_wv_w= (const float*)d_in[27];
    const float* cmp_wv_b= (const float*)d_in[28];
    const float* cmp_wa_w= (const float*)d_in[29];
    const float* out_wv_w= (const float*)d_in[31];
    const float* out_wv_b= (const float*)d_in[32];
    const float* out_wh_w= (const float*)d_in[33];
    const float* out_wh_b= (const float*)d_in[34];
    const float* out_wa_w= (const float*)d_in[35];

    float* out = (float*)d_out;
    float* h_vis    = out + BR;
    float* h_lang   = out;
    float* h_lang2  = out + 2 * BR;
    float* c_vis    = out + 3 * BR;
    float* c_lang   = out + 4 * BR;
    float* out_feats= out + 5 * BR;

    float* ws = (float*)d_ws;
    float* gates      = ws;                                  // 8 * 1048576
    float* hproj4     = gates + (size_t)8 * B_ * 4096;       // 4 * 131072
    float* base_cmp2  = hproj4 + (size_t)4 * B_ * A_;        // 131072
    float* lpart      = base_cmp2 + (size_t)B_ * A_;         // 4*16384
    float* lpart_out  = lpart + 4 * 16384;                   // 4*768
    float* logits_sp  = lpart_out + 4 * 768;                 // 16384
    float* attw_sp    = logits_sp + 16384;
    float* attw_ctx   = attw_sp + 16384;
    float* attw_cmp   = attw_ctx + 16384;
    float* attw_out   = attw_cmp + 16384;                    // 768
    float* single_feat= attw_out + 768;                      // B*R
    float* context_feat = single_feat + BR;
    float* comp_feat  = context_feat + BR;
    float* feats3     = comp_feat + BR;                      // 3*B*R

    float* hp0 = hproj4;
    float* hp1 = hproj4 + (size_t)B_ * A_;
    float* hp2 = hproj4 + (size_t)2 * B_ * A_;
    float* hp3 = hproj4 + (size_t)3 * B_ * A_;

    const dim3 blk(256);
    const int ZST = B_ * 4096;

    // ---- visual LSTM: K-concat [prev_h|fc|xt] (W_ih_v) + h0 (W_hh_v), 8x512 split-K
    {
        Seg8 s;
        s.A[0] = sh + BR;       s.W[0] = W_ih_v;          s.lda[0] = 1024; s.ldw[0] = 3072;
        s.A[1] = sh + BR + 512; s.W[1] = W_ih_v + 512;    s.lda[1] = 1024; s.ldw[1] = 3072;
        s.A[2] = fc;            s.W[2] = W_ih_v + 1024;   s.lda[2] = 1024; s.ldw[2] = 3072;
        s.A[3] = fc + 512;      s.W[3] = W_ih_v + 1536;   s.lda[3] = 1024; s.ldw[3] = 3072;
        s.A[4] = xt;            s.W[4] = W_ih_v + 2048;   s.lda[4] = 1024; s.ldw[4] = 3072;
        s.A[5] = xt + 512;      s.W[5] = W_ih_v + 2560;   s.lda[5] = 1024; s.ldw[5] = 3072;
        s.A[6] = sh;            s.W[6] = W_hh_v;          s.lda[6] = 1024; s.ldw[6] = 1024;
        s.A[7] = sh + 512;      s.W[7] = W_hh_v + 512;    s.lda[7] = 1024; s.ldw[7] = 1024;
        mm_seg<<<dim3(32, 2, 8), blk, 0, stream>>>(s, gates, 4096, 512, ZST);
    }
    lstm_pw<<<dim3(B_), blk, 0, stream>>>(gates, 8, b_ih_v, b_hh_v, sc, h_vis, nullptr, c_vis);

    // ---- 4 h_vis projections (with bias) ----
    {
        Jobs4 p;
        p.A[0] = h_vis; p.W[0] = sp_wh_w;  p.bias[0] = sp_wh_b;  p.C[0] = hp0;
        p.A[1] = h_vis; p.W[1] = ctx_wh_w; p.bias[1] = ctx_wh_b; p.C[1] = hp1;
        p.A[2] = h_vis; p.W[2] = cmp_wh_w; p.bias[2] = cmp_wh_b; p.C[2] = hp2;
        p.A[3] = h_vis; p.W[3] = out_wh_w; p.bias[3] = out_wh_b; p.C[3] = hp3;
        mm_jobs<<<dim3(4, 2, 4), blk, 0, stream>>>(p, 1024);
    }

    // ---- SingleSP ----
    attn_logits_sp<<<dim3(B_ * L_ / 4), blk, 0, stream>>>(hp0, p_roi, sp_wa_w, logits_sp);
    softmax_part<<<dim3(64), blk, 0, stream>>>(logits_sp, 1, 16384, 64, attw_sp);

    // ---- ContextSP: fused GEMM+logits (no proj materialization) ----
    mm_fused_attn<<<dim3(4, 128), blk, 0, stream>>>(ctxf, 1024, ctx_wv_w, 1024, 1024,
                                                    hp1, nullptr, ctx_wv_b, ctx_wa_w,
                                                    1.f, 16384, 64, lpart);
    softmax_part<<<dim3(64), blk, 0, stream>>>(lpart, 4, 16384, 64, attw_ctx);
    ws_one<<<dim3(B_), blk, 0, stream>>>(attw_ctx, ctxf, context_feat);

    // ---- CompSP: base_cmp2 = ctx_feat@cmp_wv^T + b ; logits = tanh(base - roi@W)
    {
        Jobs4 p;
        p.A[0] = p.A[1] = p.A[2] = p.A[3] = context_feat;
        p.W[0] = p.W[1] = p.W[2] = p.W[3] = cmp_wv_w;
        p.bias[0] = p.bias[1] = p.bias[2] = p.bias[3] = cmp_wv_b;
        p.C[0] = p.C[1] = p.C[2] = p.C[3] = base_cmp2;
        mm_jobs<<<dim3(4, 2, 1), blk, 0, stream>>>(p, 1024);
    }
    mm_fused_attn<<<dim3(4, 128), blk, 0, stream>>>(roi, 1024, cmp_wv_w, 1024, 1024,
                                                    hp2, base_cmp2, nullptr, cmp_wa_w,
                                                    -1.f, 16384, 64, lpart);
    softmax_part<<<dim3(64), blk, 0, stream>>>(lpart, 4, 16384, 64, attw_cmp);
    // single pass over roi: single_feat and comp_feat (= ctx - sum w*roi)
    ws_dual<<<dim3(B_), blk, 0, stream>>>(attw_sp, attw_cmp, roi, context_feat,
                                          single_feat, comp_feat);

    // ---- OutputSP ----
    build_feats3<<<dim3(B_ * 3), blk, 0, stream>>>(single_feat, comp_feat, fc, feats3);
    mm_fused_attn<<<dim3(4, 6), blk, 0, stream>>>(feats3, 1024, out_wv_w, 1024, 1024,
                                                  hp3, nullptr, out_wv_b, out_wa_w,
                                                  1.f, 768, 3, lpart_out);
    softmax_part<<<dim3(64), blk, 0, stream>>>(lpart_out, 4, 768, 3, attw_out);
    ws_out_k<<<dim3(B_), blk, 0, stream>>>(attw_out, feats3, out_feats);

    // ---- language LSTM: K-concat [out_feats|h_vis] (W_ih_l) + h1 (W_hh_l), 6x512
    {
        Seg8 s;
        s.A[0] = out_feats;       s.W[0] = W_ih_l;        s.lda[0] = 1024; s.ldw[0] = 2048;
        s.A[1] = out_feats + 512; s.W[1] = W_ih_l + 512;  s.lda[1] = 1024; s.ldw[1] = 2048;
        s.A[2] = h_vis;           s.W[2] = W_ih_l + 1024; s.lda[2] = 1024; s.ldw[2] = 2048;
        s.A[3] = h_vis + 512;     s.W[3] = W_ih_l + 1536; s.lda[3] = 1024; s.ldw[3] = 2048;
        s.A[4] = sh + BR;         s.W[4] = W_hh_l;        s.lda[4] = 1024; s.ldw[4] = 1024;
        s.A[5] = sh + BR + 512;   s.W[5] = W_hh_l + 512;  s.lda[5] = 1024; s.ldw[5] = 1024;
        s.A[6] = s.A[5];          s.W[6] = s.W[5];        s.lda[6] = 1024; s.ldw[6] = 1024;
        s.A[7] = s.A[5];          s.W[7] = s.W[5];        s.lda[7] = 1024; s.ldw[7] = 1024;
        mm_seg<<<dim3(32, 2, 6), blk, 0, stream>>>(s, gates, 4096, 512, ZST);
    }
    lstm_pw<<<dim3(B_), blk, 0, stream>>>(gates, 6, b_ih_l, b_hh_l, sc + BR,
                                          h_lang, h_lang2, c_lang);
}

// Round 3
// 598.123 us; speedup vs baseline: 1.1222x; 1.1222x over previous
//
#include <hip/hip_runtime.h>
#include <hip/hip_bf16.h>
#include <math.h>

#define B_ 256
#define L_ 64
#define R_ 1024
#define A_ 512
#define E_ 1024
#define BR (B_ * R_)

typedef __attribute__((ext_vector_type(8))) short short8;
typedef __attribute__((ext_vector_type(4))) float f32x4;

__device__ __forceinline__ unsigned int pkbf(float x, float y) {
    union { __hip_bfloat162 h; unsigned int u; } cv;
    cv.h = __float22bfloat162_rn(make_float2(x, y));
    return cv.u;
}

__device__ __forceinline__ float tanh_fast(float x) {
    return 1.f - 2.f / (1.f + __expf(2.f * x));
}
__device__ __forceinline__ float sigm_(float x) { return 1.f / (1.f + __expf(-x)); }

// XCD-aware bijective block swizzle (all grids are %8==0): each XCD gets a
// contiguous chunk of the original linear block order -> bn-siblings sharing
// an A-panel co-reside on one XCD L2.  (R1: cut FETCH 133->41 MB, keep.)
__device__ __forceinline__ void swz3(int& bx, int& by, int& bz) {
    int gx = gridDim.x, gy = gridDim.y, gz = gridDim.z;
    int id = (blockIdx.z * gy + blockIdx.y) * gx + blockIdx.x;
    int nwg = gx * gy * gz;
    id = (id & 7) * (nwg >> 3) + (id >> 3);
    bx = id % gx; id /= gx;
    by = id % gy; bz = id / gy;
}

// ---------------------------------------------------------------------------
// bf16 MFMA GEMM core, 64x128 tile, BK=32, double-buffered bf16 LDS with
// register prefetch (one barrier per K-iter). fp32->bf16 fused in staging
// (producer side). XOR-swizzled 16B chunks -> 0 measured bank conflicts (R0).
// R3: tile M halved (128->64) so every big GEMM grid hits 4 blocks/CU
// (16 waves, ~50% occupancy) -- the R0-R2 grids capped at 2 blocks/CU and
// were latency-bound (MfmaUtil 9%, counted-vmcnt null).
// ---------------------------------------------------------------------------
__device__ __forceinline__ void mm_core(const float* __restrict__ Abm, int lda,
                                        const float* __restrict__ Wbn, int ldw,
                                        int K, f32x4 acc[2][4])
{
    __shared__ unsigned int As[2][1024];   // per buf: 64 rows x 32 bf16
    __shared__ unsigned int Ws[2][2048];   // per buf: 128 rows x 32 bf16

    const int t = threadIdx.x;
    const int srow = t >> 3, sub = t & 7;          // srow 0..31, col-chunk 0..7
    const int half = sub & 1;
    const int csw = (sub >> 1) ^ ((srow >> 1) & 3); // row-invariant under +32
    int sidxA[2], sidxW[4];
    const float* pa[2];
    const float* pw[4];
#pragma unroll
    for (int i = 0; i < 2; ++i) {
        int row = srow + 32 * i;
        sidxA[i] = row * 16 + csw * 4 + half * 2;
        pa[i] = Abm + (size_t)row * lda + sub * 4;
    }
#pragma unroll
    for (int i = 0; i < 4; ++i) {
        int row = srow + 32 * i;
        sidxW[i] = row * 16 + csw * 4 + half * 2;
        pw[i] = Wbn + (size_t)row * ldw + sub * 4;
    }
    const int w = t >> 6, lane = t & 63;
    const int m0 = (w >> 1) * 32, n0 = (w & 1) * 64;  // 2x2 wave grid
    const int lrow = lane & 15, quad = lane >> 4;
    int aidx[2], widx[4];
#pragma unroll
    for (int i = 0; i < 2; ++i) {
        int ra = m0 + i * 16 + lrow;
        aidx[i] = ra * 16 + ((quad ^ ((ra >> 1) & 3)) << 2);
    }
#pragma unroll
    for (int i = 0; i < 4; ++i) {
        int rw = n0 + i * 16 + lrow;
        widx[i] = rw * 16 + ((quad ^ ((rw >> 1) & 3)) << 2);
    }

    float4 ra4[2], rw4[4];
#define MMC_LOAD() do { _Pragma("unroll") for (int i = 0; i < 2; ++i) { \
        ra4[i] = *(const float4*)pa[i]; pa[i] += 32; } \
        _Pragma("unroll") for (int i = 0; i < 4; ++i) { \
        rw4[i] = *(const float4*)pw[i]; pw[i] += 32; } } while (0)
#define MMC_STORE(buf) do { _Pragma("unroll") for (int i = 0; i < 2; ++i) \
        *(uint2*)(As[buf] + sidxA[i]) = make_uint2(pkbf(ra4[i].x, ra4[i].y), pkbf(ra4[i].z, ra4[i].w)); \
        _Pragma("unroll") for (int i = 0; i < 4; ++i) \
        *(uint2*)(Ws[buf] + sidxW[i]) = make_uint2(pkbf(rw4[i].x, rw4[i].y), pkbf(rw4[i].z, rw4[i].w)); } while (0)

    const int n = K >> 5;                  // all call sites have K >= 512
    MMC_LOAD();
    MMC_STORE(0);
    MMC_LOAD();
    for (int k = 0; k < n; ++k) {
        __syncthreads();                   // buf k&1 fully staged; other buf free
        short8 af[2], wf[4];
#pragma unroll
        for (int i = 0; i < 2; ++i) af[i] = *(const short8*)(As[k & 1] + aidx[i]);
#pragma unroll
        for (int i = 0; i < 4; ++i) wf[i] = *(const short8*)(Ws[k & 1] + widx[i]);
        if (k + 1 < n) {
            MMC_STORE((k + 1) & 1);        // other buffer: safe post-barrier
            if (k + 2 < n) MMC_LOAD();     // issue next global loads early
        }
#pragma unroll
        for (int mt = 0; mt < 2; ++mt)
#pragma unroll
            for (int nt = 0; nt < 4; ++nt)
                acc[mt][nt] = __builtin_amdgcn_mfma_f32_16x16x32_bf16(
                    af[mt], wf[nt], acc[mt][nt], 0, 0, 0);
    }
#undef MMC_LOAD
#undef MMC_STORE
}

__device__ __forceinline__ void mm_store(f32x4 acc[2][4], float* __restrict__ Cbm,
                                         int ldc, int bn, const float* __restrict__ bias)
{
    const int t = threadIdx.x;
    const int w = t >> 6, lane = t & 63;
    const int m0 = (w >> 1) * 32, n0 = (w & 1) * 64;
    const int lrow = lane & 15, quad = lane >> 4;
#pragma unroll
    for (int nt = 0; nt < 4; ++nt) {
        int col = bn + n0 + nt * 16 + lrow;
        float bv = bias ? bias[col] : 0.f;
#pragma unroll
        for (int mt = 0; mt < 2; ++mt) {
            int rbase = m0 + mt * 16 + quad * 4;
#pragma unroll
            for (int r = 0; r < 4; ++r)
                Cbm[(size_t)(rbase + r) * ldc + col] = acc[mt][nt][r] + bv;
        }
    }
}

// Fused attention-logit epilogue: lpart[bn_tile][row] = sum_a tanh(...)*wa[a]
// (rows per block now 64)
__device__ __forceinline__ void attn_epilogue(
    f32x4 acc[2][4], int bm, int bn, int M, int L,
    const float* __restrict__ base, const float* __restrict__ base2,
    const float* __restrict__ wbias, const float* __restrict__ wa,
    float sign, float* __restrict__ lpart)
{
    __shared__ float lsum[2][64];
    const int t = threadIdx.x;
    const int w = t >> 6, lane = t & 63;
    const int m0 = (w >> 1) * 32, n0 = (w & 1) * 64;
    const int lrow = lane & 15, quad = lane >> 4;
    float wav[4], wbv[4];
    int colv[4];
#pragma unroll
    for (int nt = 0; nt < 4; ++nt) {
        colv[nt] = bn + n0 + nt * 16 + lrow;
        wav[nt] = wa[colv[nt]];
        wbv[nt] = wbias ? wbias[colv[nt]] : 0.f;
    }
#pragma unroll
    for (int mt = 0; mt < 2; ++mt) {
#pragma unroll
        for (int r = 0; r < 4; ++r) {
            int rl = m0 + mt * 16 + quad * 4 + r;
            int row = bm + rl;
            int b = row / L;
            const float* bp = base + (size_t)b * A_;
            const float* bp2 = base2 ? base2 + (size_t)b * A_ : nullptr;
            float s = 0.f;
#pragma unroll
            for (int nt = 0; nt < 4; ++nt) {
                float v = bp[colv[nt]] + wbv[nt] + sign * acc[mt][nt][r];
                if (bp2) v += bp2[colv[nt]];
                s += tanh_fast(v) * wav[nt];
            }
            s += __shfl_xor(s, 1);
            s += __shfl_xor(s, 2);
            s += __shfl_xor(s, 4);
            s += __shfl_xor(s, 8);
            if (lrow == 0) lsum[w & 1][rl] = s;
        }
    }
    __syncthreads();
    if (t < 64)
        lpart[(size_t)(bn >> 7) * M + bm + t] = lsum[0][t] + lsum[1][t];
}

// ---------------------------------------------------------------------------
// GEMM kernels (all M-tiles are 64 rows, N-tiles 128 cols)
// ---------------------------------------------------------------------------
struct Seg8 { const float* A[8]; const float* W[8]; int lda[8]; int ldw[8]; };

// K-segmented split-K GEMM (LSTM gates): partials to Cbase + z*zstride
__global__ __launch_bounds__(256) void mm_seg(Seg8 s, float* __restrict__ Cbase,
                                              int ldc, int kchunk, int zstride)
{
    int bx, by, bz;
    swz3(bx, by, bz);
    int z = bz;
    int bm = by * 64, bn = bx * 128;
    f32x4 acc[2][4];
#pragma unroll
    for (int i = 0; i < 2; ++i)
#pragma unroll
        for (int j = 0; j < 4; ++j) acc[i][j] = (f32x4)0.f;
    mm_core(s.A[z] + (size_t)bm * s.lda[z], s.lda[z],
            s.W[z] + (size_t)bn * s.ldw[z], s.ldw[z], kchunk, acc);
    mm_store(acc, Cbase + (size_t)z * zstride + (size_t)bm * ldc, ldc, bn, nullptr);
}

// batched small GEMMs (M=256, N=512, K=1024, lda=ldw=1024, ldc=512)
struct Jobs4 { const float* A[4]; const float* W[4]; const float* bias[4]; float* C[4]; };
__global__ __launch_bounds__(256) void mm_jobs(Jobs4 p, int K)
{
    int bx, by, bz;
    swz3(bx, by, bz);
    int z = bz;
    int bm = by * 64, bn = bx * 128;
    f32x4 acc[2][4];
#pragma unroll
    for (int i = 0; i < 2; ++i)
#pragma unroll
        for (int j = 0; j < 4; ++j) acc[i][j] = (f32x4)0.f;
    mm_core(p.A[z] + (size_t)bm * 1024, 1024, p.W[z] + (size_t)bn * 1024, 1024, K, acc);
    mm_store(acc, p.C[z] + (size_t)bm * 512, 512, bn, p.bias[z]);
}

// GEMM + fused tanh-logit reduction (no C write at all)
__global__ __launch_bounds__(256) void mm_fused_attn(
    const float* __restrict__ A, int lda, const float* __restrict__ W, int ldw, int K,
    const float* __restrict__ base, const float* __restrict__ base2,
    const float* __restrict__ wbias, const float* __restrict__ wa,
    float sign, int M, int L, float* __restrict__ lpart)
{
    int bx, by, bz;
    swz3(bx, by, bz);
    int bm = by * 64, bn = bx * 128;
    f32x4 acc[2][4];
#pragma unroll
    for (int i = 0; i < 2; ++i)
#pragma unroll
        for (int j = 0; j < 4; ++j) acc[i][j] = (f32x4)0.f;
    mm_core(A + (size_t)bm * lda, lda, W + (size_t)bn * ldw, ldw, K, acc);
    attn_epilogue(acc, bm, bn, M, L, base, base2, wbias, wa, sign, lpart);
}

// ---------------------------------------------------------------------------
// pointwise kernels
// ---------------------------------------------------------------------------
__global__ __launch_bounds__(256) void attn_logits_sp(
    const float* __restrict__ base, const float* __restrict__ proj,
    const float* __restrict__ wa, float* __restrict__ logits)
{
    int idx = blockIdx.x * 4 + (threadIdx.x >> 6);   // b*64+l
    int lane = threadIdx.x & 63;
    int b = idx >> 6;
    const f32x4* p = (const f32x4*)(proj + (size_t)idx * A_);
    const f32x4* bs = (const f32x4*)(base + (size_t)b * A_);
    const f32x4* wv = (const f32x4*)wa;
    float acc = 0.f;
#pragma unroll
    for (int i = 0; i < 2; ++i) {
        int a = i * 64 + lane;
        f32x4 pv = p[a], bv = bs[a], w4 = wv[a];
#pragma unroll
        for (int j = 0; j < 4; ++j) acc += tanh_fast(bv[j] + pv[j]) * w4[j];
    }
#pragma unroll
    for (int off = 32; off > 0; off >>= 1) acc += __shfl_xor(acc, off);
    if (lane == 0) logits[idx] = acc;
}

// softmax over L (<=64) per group, summing np logit partials
__global__ __launch_bounds__(256) void softmax_part(
    const float* __restrict__ lpart, int np, int M, int L, float* __restrict__ attw)
{
    int grp = blockIdx.x * 4 + (threadIdx.x >> 6);
    int lane = threadIdx.x & 63;
    int row = grp * L + lane;
    float v = -INFINITY;
    if (lane < L) {
        float s = 0.f;
        for (int p = 0; p < np; ++p) s += lpart[(size_t)p * M + row];
        v = s;
    }
    float m = v;
#pragma unroll
    for (int off = 32; off > 0; off >>= 1) m = fmaxf(m, __shfl_xor(m, off));
    float e = (lane < L) ? __expf(v - m) : 0.f;
    float s = e;
#pragma unroll
    for (int off = 32; off > 0; off >>= 1) s += __shfl_xor(s, off);
    if (lane < L) attw[row] = e / s;
}

// out[b,:] = sum_l w[b,l] * V[b,l,:]
__global__ void ws_one(const float* __restrict__ wgt, const float* __restrict__ V,
                       float* __restrict__ out)
{
    int idx = blockIdx.x * blockDim.x + threadIdx.x;   // B*256 (float4 lanes)
    int b = idx >> 8, d4 = idx & 255;
    const f32x4* vp = (const f32x4*)(V + (size_t)b * L_ * R_) + d4;
    const float* wp = wgt + b * L_;
    f32x4 acc = (f32x4)0.f;
    for (int l = 0; l < L_; ++l) acc += wp[l] * vp[(size_t)l * 256];
    ((f32x4*)out)[idx] = acc;
}

// single pass over roi: out1 = sum w1*V ; out2 = ctx - sum w2*V
__global__ void ws_dual(const float* __restrict__ w1, const float* __restrict__ w2,
                        const float* __restrict__ V, const float* __restrict__ ctx,
                        float* __restrict__ out1, float* __restrict__ out2)
{
    int idx = blockIdx.x * blockDim.x + threadIdx.x;
    int b = idx >> 8, d4 = idx & 255;
    const f32x4* vp = (const f32x4*)(V + (size_t)b * L_ * R_) + d4;
    const float* p1 = w1 + b * L_;
    const float* p2 = w2 + b * L_;
    f32x4 a1 = (f32x4)0.f, a2 = (f32x4)0.f;
    for (int l = 0; l < L_; ++l) {
        f32x4 v = vp[(size_t)l * 256];
        a1 += p1[l] * v;
        a2 += p2[l] * v;
    }
    ((f32x4*)out1)[idx] = a1;
    ((f32x4*)out2)[idx] = ((const f32x4*)ctx)[idx] - a2;
}

__global__ void ws_out_k(const float* __restrict__ wgt, const float* __restrict__ f3,
                         float* __restrict__ out)
{
    int idx = blockIdx.x * blockDim.x + threadIdx.x;   // B*256
    int b = idx >> 8, d4 = idx & 255;
    const f32x4* fp = (const f32x4*)f3;
    f32x4 acc = (f32x4)0.f;
#pragma unroll
    for (int j = 0; j < 3; ++j)
        acc += wgt[b * 3 + j] * fp[(size_t)(b * 3 + j) * 256 + d4];
    ((f32x4*)out)[idx] = acc;
}

__global__ void build_feats3(const float* __restrict__ sf, const float* __restrict__ cf,
                             const float* __restrict__ fc, float* __restrict__ f3)
{
    int idx = blockIdx.x * blockDim.x + threadIdx.x;   // B*3*256
    int d4 = idx & 255;
    int tt = idx >> 8;
    int j = tt % 3, b = tt / 3;
    const float* src = (j == 0) ? sf : (j == 1) ? cf : fc;
    ((f32x4*)f3)[idx] = ((const f32x4*)(src + (size_t)b * R_))[d4];
}

// LSTM pointwise summing P split-K partials + both biases (float4)
__global__ void lstm_pw(const float* __restrict__ gp, int P,
                        const float* __restrict__ b_ih, const float* __restrict__ b_hh,
                        const float* __restrict__ c_prev,
                        float* __restrict__ h_out, float* __restrict__ h_out2,
                        float* __restrict__ c_out)
{
    int idx = blockIdx.x * blockDim.x + threadIdx.x;   // B*256
    int b = idx >> 8, r4 = idx & 255;
    f32x4 g[4];
#pragma unroll
    for (int gi = 0; gi < 4; ++gi) {
        int o = gi * 256 + r4;
        f32x4 s = ((const f32x4*)b_ih)[o] + ((const f32x4*)b_hh)[o];
        for (int p = 0; p < P; ++p)
            s += ((const f32x4*)(gp + (size_t)p * B_ * 4096 + (size_t)b * 4096))[o];
        g[gi] = s;
    }
    f32x4 cp = ((const f32x4*)c_prev)[idx];
    f32x4 c2, h2;
#pragma unroll
    for (int j = 0; j < 4; ++j) {
        float cc = sigm_(g[1][j]) * cp[j] + sigm_(g[0][j]) * tanh_fast(g[2][j]);
        c2[j] = cc;
        h2[j] = sigm_(g[3][j]) * tanh_fast(cc);
    }
    ((f32x4*)c_out)[idx] = c2;
    ((f32x4*)h_out)[idx] = h2;
    if (h_out2) ((f32x4*)h_out2)[idx] = h2;
}

// ---------------------------------------------------------------------------
extern "C" void kernel_launch(void* const* d_in, const int* in_sizes, int n_in,
                              void* d_out, int out_size, void* d_ws, size_t ws_size,
                              hipStream_t stream)
{
    const float* xt      = (const float*)d_in[0];
    const float* fc      = (const float*)d_in[1];
    const float* roi     = (const float*)d_in[2];
    const float* p_roi   = (const float*)d_in[3];
    const float* ctxf    = (const float*)d_in[4];
    const float* sh      = (const float*)d_in[5];
    const float* sc      = (const float*)d_in[6];
    const float* W_ih_v  = (const float*)d_in[7];
    const float* W_hh_v  = (const float*)d_in[8];
    const float* b_ih_v  = (const float*)d_in[9];
    const float* b_hh_v  = (const float*)d_in[10];
    const float* W_ih_l  = (const float*)d_in[11];
    const float* W_hh_l  = (const float*)d_in[12];
    const float* b_ih_l  = (const float*)d_in[13];
    const float* b_hh_l  = (const float*)d_in[14];
    const float* sp_wh_w = (const float*)d_in[15];
    const float* sp_wh_b = (const float*)d_in[16];
    const float* sp_wa_w = (const float*)d_in[17];
    const float* ctx_wh_w= (const float*)d_in[19];
    const float* ctx_wh_b= (const float*)d_in[20];
    const float* ctx_wv_w= (const float*)d_in[21];
    const float* ctx_wv_b= (const float*)d_in[22];
    const float* ctx_wa_w= (const float*)d_in[23];
    const float* cmp_wh_w= (const float*)d_in[25];
    const float* cmp_wh_b= (const float*)d_in[26];
    const float* cmp_wv_w= (const float*)d_in[27];
    const float* cmp_wv_b= (const float*)d_in[28];
    const float* cmp_wa_w= (const float*)d_in[29];
    const float* out_wv_w= (const float*)d_in[31];
    const float* out_wv_b= (const float*)d_in[32];
    const float* out_wh_w= (const float*)d_in[33];
    const float* out_wh_b= (const float*)d_in[34];
    const float* out_wa_w= (const float*)d_in[35];

    float* out = (float*)d_out;
    float* h_vis    = out + BR;
    float* h_lang   = out;
    float* h_lang2  = out + 2 * BR;
    float* c_vis    = out + 3 * BR;
    float* c_lang   = out + 4 * BR;
    float* out_feats= out + 5 * BR;

    float* ws = (float*)d_ws;
    float* gates      = ws;                                  // 8 * 1048576
    float* hproj4     = gates + (size_t)8 * B_ * 4096;       // 4 * 131072
    float* base_cmp2  = hproj4 + (size_t)4 * B_ * A_;        // 131072
    float* lpart      = base_cmp2 + (size_t)B_ * A_;         // 4*16384
    float* lpart_out  = lpart + 4 * 16384;                   // 4*768
    float* logits_sp  = lpart_out + 4 * 768;                 // 16384
    float* attw_sp    = logits_sp + 16384;
    float* attw_ctx   = attw_sp + 16384;
    float* attw_cmp   = attw_ctx + 16384;
    float* attw_out   = attw_cmp + 16384;                    // 768
    float* single_feat= attw_out + 768;                      // B*R
    float* context_feat = single_feat + BR;
    float* comp_feat  = context_feat + BR;
    float* feats3     = comp_feat + BR;                      // 3*B*R

    float* hp0 = hproj4;
    float* hp1 = hproj4 + (size_t)B_ * A_;
    float* hp2 = hproj4 + (size_t)2 * B_ * A_;
    float* hp3 = hproj4 + (size_t)3 * B_ * A_;

    const dim3 blk(256);
    const int ZST = B_ * 4096;

    // ---- visual LSTM: K-concat [prev_h|fc|xt] (W_ih_v) + h0 (W_hh_v), 8x512 split-K
    {
        Seg8 s;
        s.A[0] = sh + BR;       s.W[0] = W_ih_v;          s.lda[0] = 1024; s.ldw[0] = 3072;
        s.A[1] = sh + BR + 512; s.W[1] = W_ih_v + 512;    s.lda[1] = 1024; s.ldw[1] = 3072;
        s.A[2] = fc;            s.W[2] = W_ih_v + 1024;   s.lda[2] = 1024; s.ldw[2] = 3072;
        s.A[3] = fc + 512;      s.W[3] = W_ih_v + 1536;   s.lda[3] = 1024; s.ldw[3] = 3072;
        s.A[4] = xt;            s.W[4] = W_ih_v + 2048;   s.lda[4] = 1024; s.ldw[4] = 3072;
        s.A[5] = xt + 512;      s.W[5] = W_ih_v + 2560;   s.lda[5] = 1024; s.ldw[5] = 3072;
        s.A[6] = sh;            s.W[6] = W_hh_v;          s.lda[6] = 1024; s.ldw[6] = 1024;
        s.A[7] = sh + 512;      s.W[7] = W_hh_v + 512;    s.lda[7] = 1024; s.ldw[7] = 1024;
        mm_seg<<<dim3(32, 4, 8), blk, 0, stream>>>(s, gates, 4096, 512, ZST);
    }
    lstm_pw<<<dim3(B_), blk, 0, stream>>>(gates, 8, b_ih_v, b_hh_v, sc, h_vis, nullptr, c_vis);

    // ---- 4 h_vis projections (with bias) ----
    {
        Jobs4 p;
        p.A[0] = h_vis; p.W[0] = sp_wh_w;  p.bias[0] = sp_wh_b;  p.C[0] = hp0;
        p.A[1] = h_vis; p.W[1] = ctx_wh_w; p.bias[1] = ctx_wh_b; p.C[1] = hp1;
        p.A[2] = h_vis; p.W[2] = cmp_wh_w; p.bias[2] = cmp_wh_b; p.C[2] = hp2;
        p.A[3] = h_vis; p.W[3] = out_wh_w; p.bias[3] = out_wh_b; p.C[3] = hp3;
        mm_jobs<<<dim3(4, 4, 4), blk, 0, stream>>>(p, 1024);
    }

    // ---- SingleSP ----
    attn_logits_sp<<<dim3(B_ * L_ / 4), blk, 0, stream>>>(hp0, p_roi, sp_wa_w, logits_sp);
    softmax_part<<<dim3(64), blk, 0, stream>>>(logits_sp, 1, 16384, 64, attw_sp);

    // ---- ContextSP: fused GEMM+logits (no proj materialization) ----
    mm_fused_attn<<<dim3(4, 256), blk, 0, stream>>>(ctxf, 1024, ctx_wv_w, 1024, 1024,
                                                    hp1, nullptr, ctx_wv_b, ctx_wa_w,
                                                    1.f, 16384, 64, lpart);
    softmax_part<<<dim3(64), blk, 0, stream>>>(lpart, 4, 16384, 64, attw_ctx);
    ws_one<<<dim3(B_), blk, 0, stream>>>(attw_ctx, ctxf, context_feat);

    // ---- CompSP: base_cmp2 = ctx_feat@cmp_wv^T + b ; logits = tanh(base - roi@W)
    {
        Jobs4 p;
        p.A[0] = p.A[1] = p.A[2] = p.A[3] = context_feat;
        p.W[0] = p.W[1] = p.W[2] = p.W[3] = cmp_wv_w;
        p.bias[0] = p.bias[1] = p.bias[2] = p.bias[3] = cmp_wv_b;
        p.C[0] = p.C[1] = p.C[2] = p.C[3] = base_cmp2;
        mm_jobs<<<dim3(4, 4, 1), blk, 0, stream>>>(p, 1024);
    }
    mm_fused_attn<<<dim3(4, 256), blk, 0, stream>>>(roi, 1024, cmp_wv_w, 1024, 1024,
                                                    hp2, base_cmp2, nullptr, cmp_wa_w,
                                                    -1.f, 16384, 64, lpart);
    softmax_part<<<dim3(64), blk, 0, stream>>>(lpart, 4, 16384, 64, attw_cmp);
    // single pass over roi: single_feat and comp_feat (= ctx - sum w*roi)
    ws_dual<<<dim3(B_), blk, 0, stream>>>(attw_sp, attw_cmp, roi, context_feat,
                                          single_feat, comp_feat);

    // ---- OutputSP ----
    build_feats3<<<dim3(B_ * 3), blk, 0, stream>>>(single_feat, comp_feat, fc, feats3);
    mm_fused_attn<<<dim3(4, 12), blk, 0, stream>>>(feats3, 1024, out_wv_w, 1024, 1024,
                                                   hp3, nullptr, out_wv_b, out_wa_w,
                                                   1.f, 768, 3, lpart_out);
    softmax_part<<<dim3(64), blk, 0, stream>>>(lpart_out, 4, 768, 3, attw_out);
    ws_out_k<<<dim3(B_), blk, 0, stream>>>(attw_out, feats3, out_feats);

    // ---- language LSTM: K-concat [out_feats|h_vis] (W_ih_l) + h1 (W_hh_l), 6x512
    {
        Seg8 s;
        s.A[0] = out_feats;       s.W[0] = W_ih_l;        s.lda[0] = 1024; s.ldw[0] = 2048;
        s.A[1] = out_feats + 512; s.W[1] = W_ih_l + 512;  s.lda[1] = 1024; s.ldw[1] = 2048;
        s.A[2] = h_vis;           s.W[2] = W_ih_l + 1024; s.lda[2] = 1024; s.ldw[2] = 2048;
        s.A[3] = h_vis + 512;     s.W[3] = W_ih_l + 1536; s.lda[3] = 1024; s.ldw[3] = 2048;
        s.A[4] = sh + BR;         s.W[4] = W_hh_l;        s.lda[4] = 1024; s.ldw[4] = 1024;
        s.A[5] = sh + BR + 512;   s.W[5] = W_hh_l + 512;  s.lda[5] = 1024; s.ldw[5] = 1024;
        s.A[6] = s.A[5];          s.W[6] = s.W[5];        s.lda[6] = 1024; s.ldw[6] = 1024;
        s.A[7] = s.A[5];          s.W[7] = s.W[5];        s.lda[7] = 1024; s.ldw[7] = 1024;
        mm_seg<<<dim3(32, 4, 6), blk, 0, stream>>>(s, gates, 4096, 512, ZST);
    }
    lstm_pw<<<dim3(B_), blk, 0, stream>>>(gates, 6, b_ih_l, b_hh_l, sc + BR,
                                          h_lang, h_lang2, c_lang);
}